// Round 4
// baseline (62.379 us; speedup 1.0000x reference)
//
#include <hip/hip_runtime.h>

#define H_DIM 3072
#define W_DIM 3072
#define TW 32          // output tile width
#define TH 32          // output tile height
#define BB_ROWS 42     // max bbox rows: 31*(cos+sin)<=39.73 for theta in [0,20deg] -> +2
#define BB_STRIDE 133  // floats per LDS row: 42 cols * 3ch = 126 + 6 zero-pad + 1;
                       // odd (133 mod 32 = 5) to spread banks across ty lanes

typedef float f32x4 __attribute__((ext_vector_type(4)));
typedef f32x4 __attribute__((aligned(4))) f32x4u;  // tap bases are only 4B-aligned

__global__ __launch_bounds__(256) void rotation_kernel(
    const float* __restrict__ img,     // (H, W, 3) f32
    const float* __restrict__ fv,      // (1,) f32
    float* __restrict__ out)           // (H, W, 3) f32
{
    __shared__ float S[BB_ROWS * BB_STRIDE];   // 22,344 B -> 7 blocks/CU

    const int tx = threadIdx.x;   // 0..7  : 4 consecutive px each
    const int ty = threadIdx.y;   // 0..31 : output row within tile
    const int C0 = blockIdx.x * TW;
    const int R0 = blockIdx.y * TH;

    const float theta = fv[0] * 20.0f * (3.14159265358979323846f / 180.0f);
    const float ct = cosf(theta);
    const float st = sinf(theta);
    const float o_r = (float)H_DIM / 2.0f + 0.5f;   // 1536.5
    const float o_c = (float)W_DIM / 2.0f + 0.5f;

    // ---- block-uniform bbox of source coords (affine -> extrema at corners) ----
    const float drA = (float)R0 - o_r, drB = (float)(R0 + TH - 1) - o_r;
    const float dcA = (float)C0 - o_c, dcB = (float)(C0 + TW - 1) - o_c;
    float min_r = 1e30f, max_r = -1e30f, min_c = 1e30f, max_c = -1e30f;
    #pragma unroll
    for (int k = 0; k < 4; ++k) {
        const float dr = (k & 1) ? drB : drA;
        const float dc = (k & 2) ? dcB : dcA;
        const float sr = ct * dr - st * dc + o_r;
        const float sc = st * dr + ct * dc + o_c;
        min_r = fminf(min_r, sr); max_r = fmaxf(max_r, sr);
        min_c = fminf(min_c, sc); max_c = fmaxf(max_c, sc);
    }
    const int r_lo = min(max((int)floorf(min_r), 0), H_DIM - 1);
    const int c_lo = min(max((int)floorf(min_c), 0), W_DIM - 1);
    const int r_hi = min(min(max((int)floorf(max_r), 0), H_DIM - 1) + 1, H_DIM - 1);
    const int c_hi = min(min(max((int)floorf(max_c), 0), W_DIM - 1) + 1, W_DIM - 1);
    const int nrows = r_hi - r_lo + 1;          // <= 42
    const int nflt  = (c_hi - c_lo + 1) * 3;    // <= 126
    const int nflt4 = nflt >> 2;
    const int rem   = nflt & 3;

    // ---- stage bbox into LDS: 8 lanes per row, 32 rows in flight ----
    for (int yy = ty; yy < nrows; yy += 32) {
        const float* src = img + ((size_t)(r_lo + yy) * W_DIM + c_lo) * 3;
        float* dst = S + yy * BB_STRIDE;
        for (int xx = tx; xx < nflt4; xx += 8) {
            const f32x4u v = *(const f32x4u*)(src + xx * 4);
            // odd stride -> 4B-aligned only; scalar writes merge to ds_write2_b32
            dst[xx * 4 + 0] = v[0];
            dst[xx * 4 + 1] = v[1];
            dst[xx * 4 + 2] = v[2];
            dst[xx * 4 + 3] = v[3];
        }
        if (tx < rem) dst[nflt4 * 4 + tx] = src[nflt4 * 4 + tx];
        if (tx < 6)   dst[nflt + tx] = 0.0f;   // pad: degenerate-bbox reads see 0, not garbage
    }
    __syncthreads();

    // ---- gather from LDS: 4 consecutive px/thread, 6-float span per row ----
    const int r = R0 + ty;
    const float drr = (float)r - o_r;
    float res[12];

    #pragma unroll
    for (int p = 0; p < 4; ++p) {
        const int c = C0 + tx * 4 + p;
        const float dcc = (float)c - o_c;

        float src_r = ct * drr - st * dcc + o_r;
        float src_c = st * drr + ct * dcc + o_c;
        src_r = fminf(fmaxf(src_r, 0.0f), (float)(H_DIM - 1));
        src_c = fminf(fmaxf(src_c, 0.0f), (float)(W_DIM - 1));

        const float r0f = floorf(src_r);
        const float c0f = floorf(src_c);
        const float wr = src_r - r0f;
        const float wc = src_c - c0f;

        const int r0 = (int)r0f;
        const int c0 = (int)c0f;
        const int r1 = min(r0 + 1, H_DIM - 1);
        // clamp the 2-col window base into the staged range; when c0 lands on
        // the window's last col (right-edge clamp), wc==0 and `hi` re-selects.
        int cb = min(c0, c_hi - 1);
        cb = max(cb, c_lo);
        const bool hi = (c0 > cb);

        const int ly0 = min(max(r0 - r_lo, 0), BB_ROWS - 1);
        const int ly1 = min(max(r1 - r_lo, 0), BB_ROWS - 1);
        const int lx  = min(max((cb - c_lo) * 3, 0), BB_STRIDE - 6);

        const float* s0 = S + ly0 * BB_STRIDE + lx;
        const float* s1 = S + ly1 * BB_STRIDE + lx;
        // 6 consecutive floats per row -> 3x ds_read2_b32 each
        float q00 = s0[0], q01 = s0[1], q02 = s0[2], q03 = s0[3], q04 = s0[4], q05 = s0[5];
        float q10 = s1[0], q11 = s1[1], q12 = s1[2], q13 = s1[3], q14 = s1[4], q15 = s1[5];
        if (hi) { q00 = q03; q01 = q04; q02 = q05; q10 = q13; q11 = q14; q12 = q15; }

        float row0, row1;
        row0 = q00 + wc * (q03 - q00); row1 = q10 + wc * (q13 - q10);
        res[p * 3 + 0] = row0 + wr * (row1 - row0);
        row0 = q01 + wc * (q04 - q01); row1 = q11 + wc * (q14 - q11);
        res[p * 3 + 1] = row0 + wr * (row1 - row0);
        row0 = q02 + wc * (q05 - q02); row1 = q12 + wc * (q15 - q12);
        res[p * 3 + 2] = row0 + wr * (row1 - row0);
    }

    // 48 contiguous bytes per thread, 16B-aligned: 3x dwordx4 stores
    float4* op = (float4*)(out + ((size_t)r * W_DIM + C0 + tx * 4) * 3);
    op[0] = make_float4(res[0], res[1], res[2],  res[3]);
    op[1] = make_float4(res[4], res[5], res[6],  res[7]);
    op[2] = make_float4(res[8], res[9], res[10], res[11]);
}

extern "C" void kernel_launch(void* const* d_in, const int* in_sizes, int n_in,
                              void* d_out, int out_size, void* d_ws, size_t ws_size,
                              hipStream_t stream) {
    const float* img = (const float*)d_in[0];
    const float* fv  = (const float*)d_in[1];
    float* out = (float*)d_out;

    dim3 block(8, 32, 1);
    dim3 grid(W_DIM / TW, H_DIM / TH, 1);
    rotation_kernel<<<grid, block, 0, stream>>>(img, fv, out);
}

// Round 5
// 49.650 us; speedup vs baseline: 1.2564x; 1.2564x over previous
//
#include <hip/hip_runtime.h>

#define H_DIM 3072
#define W_DIM 3072

// 4B-aligned vector types: tap base addrs ((r*W+c)*3 floats) are only 4B-aligned.
typedef float f32x4 __attribute__((ext_vector_type(4)));
typedef float f32x2 __attribute__((ext_vector_type(2)));
typedef f32x4 __attribute__((aligned(4))) f32x4u;
typedef f32x2 __attribute__((aligned(4))) f32x2u;

__global__ __launch_bounds__(256) void rotation_kernel(
    const float* __restrict__ img,     // (H, W, 3) f32
    const float* __restrict__ fv,      // (1,) f32
    float* __restrict__ out)           // (H, W, 3) f32
{
    // 128x8 tile per block, 4 consecutive px per thread.
    const int c_base = (blockIdx.x * 32 + threadIdx.x) * 4;
    const int r      = blockIdx.y * 8 + threadIdx.y;

    // HW transcendentals: theta in [0, 0.349] rad; v_cos/v_sin error ~4 ULP
    // -> sample-coord error ~2e-4 px -> output error ~1e-3, threshold 0.103.
    const float theta = fv[0] * 20.0f * (3.14159265358979323846f / 180.0f);
    const float ct = __cosf(theta);
    const float st = __sinf(theta);

    const float o_r = (float)H_DIM / 2.0f + 0.5f;   // 1536.5
    const float o_c = (float)W_DIM / 2.0f + 0.5f;
    const float dr = (float)r - o_r;

    // ---- phase 1: coords + addresses for all 4 px (fully unrolled -> regs) ----
    float wrv[4], wcv[4];
    bool  hiv[4];
    const float* rp0[4];
    const float* rp1[4];

    #pragma unroll
    for (int p = 0; p < 4; ++p) {
        const int c = c_base + p;
        const float dc = (float)c - o_c;

        float src_r = ct * dr - st * dc + o_r;
        float src_c = st * dr + ct * dc + o_c;
        src_r = fminf(fmaxf(src_r, 0.0f), (float)(H_DIM - 1));
        src_c = fminf(fmaxf(src_c, 0.0f), (float)(W_DIM - 1));

        const float r0f = floorf(src_r);
        const float c0f = floorf(src_c);
        wrv[p] = src_r - r0f;
        wcv[p] = src_c - c0f;

        const int r0 = (int)r0f;
        const int c0 = (int)c0f;
        const int r1 = min(r0 + 1, H_DIM - 1);
        // clamp 2-px window base so the 6-float segment stays in-bounds;
        // when c0==W-1, wc==0 exactly, `hi` re-selects the valid pixel.
        const int cb = min(c0, W_DIM - 2);
        hiv[p] = (c0 > cb);

        rp0[p] = img + ((size_t)r0 * W_DIM + cb) * 3;
        rp1[p] = img + ((size_t)r1 * W_DIM + cb) * 3;
    }

    // ---- phase 2: issue ALL 16 segment loads back-to-back (latency batching) ----
    f32x4u A0[4], A1[4];
    f32x2u B0[4], B1[4];
    #pragma unroll
    for (int p = 0; p < 4; ++p) {
        A0[p] = *(const f32x4u*)rp0[p];
        B0[p] = *(const f32x2u*)(rp0[p] + 4);
        A1[p] = *(const f32x4u*)rp1[p];
        B1[p] = *(const f32x2u*)(rp1[p] + 4);
    }

    // ---- phase 3: blend ----
    float res[12];
    #pragma unroll
    for (int p = 0; p < 4; ++p) {
        const float q0[6] = {A0[p][0], A0[p][1], A0[p][2], A0[p][3], B0[p][0], B0[p][1]};
        const float q1[6] = {A1[p][0], A1[p][1], A1[p][2], A1[p][3], B1[p][0], B1[p][1]};
        const float wr = wrv[p], wc = wcv[p];
        const bool hi = hiv[p];
        #pragma unroll
        for (int ch = 0; ch < 3; ++ch) {
            const float t00 = hi ? q0[3 + ch] : q0[ch];
            const float t10 = hi ? q1[3 + ch] : q1[ch];
            const float t01 = q0[3 + ch];
            const float t11 = q1[3 + ch];
            const float row0 = t00 + wc * (t01 - t00);
            const float row1 = t10 + wc * (t11 - t10);
            res[p * 3 + ch] = row0 + wr * (row1 - row0);
        }
    }

    // 48 contiguous bytes per thread, 16B-aligned: 3x dwordx4 stores.
    float4* op = (float4*)(out + ((size_t)r * W_DIM + c_base) * 3);
    op[0] = make_float4(res[0], res[1], res[2],  res[3]);
    op[1] = make_float4(res[4], res[5], res[6],  res[7]);
    op[2] = make_float4(res[8], res[9], res[10], res[11]);
}

extern "C" void kernel_launch(void* const* d_in, const int* in_sizes, int n_in,
                              void* d_out, int out_size, void* d_ws, size_t ws_size,
                              hipStream_t stream) {
    const float* img = (const float*)d_in[0];
    const float* fv  = (const float*)d_in[1];
    float* out = (float*)d_out;

    dim3 block(32, 8, 1);
    dim3 grid(W_DIM / 128, H_DIM / 8, 1);
    rotation_kernel<<<grid, block, 0, stream>>>(img, fv, out);
}